// Round 2
// 177.571 us; speedup vs baseline: 1.0166x; 1.0166x over previous
//
#include <hip/hip_runtime.h>

#define N_NODES 20000
#define N_EDGES 640000
#define DIM 128
#define NGRAPH 64
#define NBUCK 313          // ceil(20000/64) dst buckets of 64 nodes
#define CAP 2560           // padded records per bucket (mean 2048, 11 sigma)
#define EPB 1024           // edges per partition chunk
#define NB_PART 625        // ceil(640000/1024)
#define NB_WCONV 32
#define NB_GEMM 1252       // 313 row-tiles x 4 col-tiles
#define RED_BLOCKS 512

typedef __attribute__((ext_vector_type(8))) short short8;
typedef __attribute__((ext_vector_type(4))) float floatx4;
typedef __attribute__((ext_vector_type(4))) int intx4;

__device__ __forceinline__ unsigned int bf16rne(float f) {
    unsigned int u = __float_as_uint(f);
    return (u + 0x7FFFu + ((u >> 16) & 1u)) >> 16;
}

// streaming (read-once) int2 load with non-temporal hint
__device__ __forceinline__ int2 nt_load2(const int2* p) {
    long long v = __builtin_nontemporal_load((const long long*)p);
    int2 r;
    r.x = (int)(v & 0xFFFFFFFFll);
    r.y = (int)(v >> 32);
    return r;
}

// streaming 16B load (2 edge records) — caller guarantees 16B alignment
__device__ __forceinline__ intx4 nt_load4(const int2* p) {
    return __builtin_nontemporal_load((const intx4*)p);
}

// ---------------------------------------------------------------------------
// K1: fused [edge partition into fixed-capacity buckets | weight split-bf16
// convert | params]. No histogram/scan pass: bucket b owns part[b*CAP ..).
// record.x = (dst<<16)|src
// ---------------------------------------------------------------------------
__global__ __launch_bounds__(256) void k_part_prep(
    const int* __restrict__ src, const int* __restrict__ dst,
    const float* __restrict__ ew,
    const float* __restrict__ W1rel, const float* __restrict__ W1root,
    const float* __restrict__ W3rel, const float* __restrict__ W3root,
    const float* __restrict__ b3, const float* __restrict__ Wlin,
    int* __restrict__ gcursor, int2* __restrict__ part,
    unsigned short* __restrict__ wbh, unsigned short* __restrict__ wbl,
    float* __restrict__ vrel, float* __restrict__ vroot, float* __restrict__ cb3) {

    const int t = threadIdx.x;
    const int blk = blockIdx.x;

    if (blk < NB_PART) {
        __shared__ int lhist[NBUCK], lbase[NBUCK], gbase[NBUCK], lcur[NBUCK];
        __shared__ int2 lrec[EPB];   // 8 KB
        for (int i = t; i < NBUCK; i += 256) lhist[i] = 0;
        __syncthreads();
        const int e0 = blk * EPB;
        const int tot = min(EPB, N_EDGES - e0);
        int mys[4], myd[4];
        float myw[4];
        for (int i = 0; i < 4; ++i) {
            int e = e0 + i * 256 + t;
            if (e < N_EDGES) {
                mys[i] = src[e];
                myd[i] = dst[e];
                myw[i] = ew[e];
                atomicAdd(&lhist[myd[i] >> 6], 1);
            } else {
                myd[i] = -1;
            }
        }
        __syncthreads();
        // local exclusive scan over bucket counts (one wave)
        if (t < 64) {
            int carry = 0;
            for (int c = 0; c < 5; ++c) {
                int idx = c * 64 + t;
                int v = (idx < NBUCK) ? lhist[idx] : 0;
                int xv = v;
                for (int s = 1; s < 64; s <<= 1) {
                    int u = __shfl_up(xv, s);
                    if (t >= s) xv += u;
                }
                if (idx < NBUCK) { lbase[idx] = carry + xv - v; lcur[idx] = 0; }
                carry += __shfl(xv, 63);
            }
        }
        __syncthreads();
        // reserve bucket ranges (gcursor[b] counts records; region = b*CAP)
        for (int i = t; i < NBUCK; i += 256) {
            int cnt = lhist[i];
            gbase[i] = cnt ? (i * CAP + atomicAdd(&gcursor[i], cnt)) : 0;
        }
        __syncthreads();
        // bucket-sort into LDS
        for (int i = 0; i < 4; ++i) {
            if (myd[i] >= 0) {
                int bb = myd[i] >> 6;
                int slot = lbase[bb] + atomicAdd(&lcur[bb], 1);
                lrec[slot] = make_int2((myd[i] << 16) | mys[i], __float_as_int(myw[i]));
            }
        }
        __syncthreads();
        // coalesced write-out of bucket runs
        for (int i = t; i < tot; i += 256) {
            int2 rc = lrec[i];
            int bb = ((unsigned)rc.x >> 16) >> 6;
            part[gbase[bb] + (i - lbase[bb])] = rc;
        }
    } else if (blk < NB_PART + NB_WCONV) {
        const int b = blk - NB_PART;
        for (int i = b * 256 + t; i < 256 * DIM; i += NB_WCONV * 256) {
            int n = i >> 7, k = i & 127;
            float v = (n < DIM) ? W1rel[n * DIM + k] : W1root[(n - DIM) * DIM + k];
            unsigned int h = bf16rne(v);
            wbh[i] = (unsigned short)h;
            wbl[i] = (unsigned short)bf16rne(v - __uint_as_float(h << 16));
        }
    } else {
        if (t < 64) {
            for (int kk = 0; kk < 2; ++kk) {
                int k = t + kk * 64;
                float sr = 0.f, so = 0.f;
                for (int h = 0; h < DIM; ++h) {
                    float wl = Wlin[h];
                    sr = fmaf(wl, W3rel[h * DIM + k], sr);
                    so = fmaf(wl, W3root[h * DIM + k], so);
                }
                vrel[k] = sr;
                vroot[k] = so;
            }
            float c = b3[t] * Wlin[t] + b3[t + 64] * Wlin[t + 64];
            for (int m = 32; m > 0; m >>= 1) c += __shfl_xor(c, m);
            if (t == 0) cb3[0] = c;
        }
    }
}

// ---------------------------------------------------------------------------
// K2: fused [in-place bucket counting-sort -> off/nend | split-bf16 MFMA GEMM]
// Both depend only on K1. LDS union 32 KB -> 4 blocks/CU.
// ---------------------------------------------------------------------------
union SMem2 {
    struct { int2 lrec[CAP]; int nh[64], ncur[64]; } s;       // 20992 B
    struct { unsigned short h[64 * DIM], l[64 * DIM]; } g;    // 32768 B
};

__global__ __launch_bounds__(256) void k_sort_gemm(
    const int* __restrict__ gcursor, int2* __restrict__ part,
    int* __restrict__ off, int* __restrict__ nend,
    const float* __restrict__ x,
    const unsigned short* __restrict__ wbh, const unsigned short* __restrict__ wbl,
    const float* __restrict__ b1,
    unsigned short* __restrict__ yb, float* __restrict__ r) {
    __shared__ SMem2 sm;
    const int t = threadIdx.x;

    if (blockIdx.x < NBUCK) {
        // ---------------- bucketsort (in place) ----------------
        const int b = blockIdx.x;
        const int base = b * CAP;
        const int cnt = min(gcursor[b], CAP);
        for (int i = t; i < cnt; i += 256) sm.s.lrec[i] = nt_load2(&part[base + i]);
        if (t < 64) sm.s.nh[t] = 0;
        __syncthreads();
        for (int i = t; i < cnt; i += 256)
            atomicAdd(&sm.s.nh[((unsigned)sm.s.lrec[i].x >> 16) & 63], 1);
        __syncthreads();
        if (t < 64) {
            int v = sm.s.nh[t];
            int xv = v;
            for (int s = 1; s < 64; s <<= 1) {
                int u = __shfl_up(xv, s);
                if (t >= s) xv += u;
            }
            int excl = xv - v;
            sm.s.ncur[t] = excl;
            int node = b * 64 + t;
            if (node < N_NODES) {
                off[node] = base + excl;
                nend[node] = base + excl + v;
            }
        }
        __syncthreads();
        for (int i = t; i < cnt; i += 256) {
            int2 rc = sm.s.lrec[i];
            int dl = ((unsigned)rc.x >> 16) & 63;
            int p = atomicAdd(&sm.s.ncur[dl], 1);
            part[base + p] = make_int2(rc.x & 0xFFFF, rc.y);
        }
    } else {
        // ---------------- GEMM 64-row x 64-col tile ----------------
        const int tile = blockIdx.x - NBUCK;
        const int g = tile >> 2;
        const int col0 = (tile & 3) * 64;
        uint4* sh = (uint4*)sm.g.h;
        uint4* sl = (uint4*)sm.g.l;
        const uint4* gh = (const uint4*)wbh + (size_t)col0 * 16;
        const uint4* gl = (const uint4*)wbl + (size_t)col0 * 16;
        for (int i = t; i < 1024; i += 256) {
            int row = i >> 4, c = i & 15;
            int sc = row * 16 + (c ^ (row & 15));
            sh[sc] = gh[i];
            sl[sc] = gl[i];
        }
        __syncthreads();

        const int lane = t & 63;
        const int m = lane & 15;
        const int q = lane >> 4;
        const int row0 = g * 64 + (t >> 6) * 16;
        const int row = row0 + m;
        const bool ok = row < N_NODES;
        const short8* SH = (const short8*)sm.g.h;
        const short8* SL = (const short8*)sm.g.l;

        floatx4 acc[4];
        #pragma unroll
        for (int i = 0; i < 4; ++i) acc[i] = (floatx4)(0.f);

        #pragma unroll
        for (int kc = 0; kc < 4; ++kc) {
            float4 v0 = make_float4(0.f, 0.f, 0.f, 0.f);
            float4 v1 = make_float4(0.f, 0.f, 0.f, 0.f);
            if (ok) {
                const float4* xp = (const float4*)(x + (size_t)row * DIM + kc * 32 + q * 8);
                v0 = xp[0];
                v1 = xp[1];
            }
            float f[8] = {v0.x, v0.y, v0.z, v0.w, v1.x, v1.y, v1.z, v1.w};
            short8 ah, al;
            #pragma unroll
            for (int i = 0; i < 8; ++i) {
                unsigned int h = bf16rne(f[i]);
                ah[i] = (short)h;
                al[i] = (short)bf16rne(f[i] - __uint_as_float(h << 16));
            }
            #pragma unroll
            for (int nt = 0; nt < 4; ++nt) {
                int nl = nt * 16 + m;
                int cc = (kc * 4 + q) ^ m;
                short8 bh = SH[nl * 16 + cc];
                short8 bl = SL[nl * 16 + cc];
                acc[nt] = __builtin_amdgcn_mfma_f32_16x16x32_bf16(ah, bh, acc[nt], 0, 0, 0);
                acc[nt] = __builtin_amdgcn_mfma_f32_16x16x32_bf16(al, bh, acc[nt], 0, 0, 0);
                acc[nt] = __builtin_amdgcn_mfma_f32_16x16x32_bf16(ah, bl, acc[nt], 0, 0, 0);
            }
        }

        // epilogue: C/D layout col=lane&15, row=q*4+reg
        #pragma unroll
        for (int nt = 0; nt < 4; ++nt) {
            int col = col0 + nt * 16 + m;
            float bias = (col >= DIM) ? b1[col - DIM] : 0.f;
            #pragma unroll
            for (int reg = 0; reg < 4; ++reg) {
                int orow = row0 + q * 4 + reg;
                if (orow < N_NODES) {
                    float v = acc[nt][reg];
                    if (col < DIM)
                        yb[orow * DIM + col] = (unsigned short)bf16rne(v);
                    else
                        r[orow * DIM + (col - DIM)] = v + bias;
                }
            }
        }
    }
}

// ---------------------------------------------------------------------------
// K3: agg — wave per node, split into two 32-lane halves that each own 4 dims
// per lane (uint2 = 8B payload per lane => ONE gather instruction moves TWO
// edges' 256B rows). Edge records fetched as dwordx4 (2 records/instr) after
// peeling one edge to force 16B alignment. 6 VMEM instrs per 8 edges (was 16).
// h1=relu(agg+r); a,b dots; halves merged with one shfl_xor(32).
// ---------------------------------------------------------------------------
__global__ __launch_bounds__(256) void k_agg(const uint2* __restrict__ yb2,
                                             const float4* __restrict__ r4,
                                             const int* __restrict__ off,
                                             const int* __restrict__ nend,
                                             const int2* __restrict__ grec,
                                             const float4* __restrict__ vrel4,
                                             const float4* __restrict__ vroot4,
                                             float* __restrict__ aout,
                                             float* __restrict__ bout) {
    const int lane = threadIdx.x & 63;
    const int half = lane >> 5;
    const int c = lane & 31;                       // dim group: dims 4c..4c+3
    const int node = blockIdx.x * 4 + (threadIdx.x >> 6);
    if (node >= N_NODES) return;

    // hoist independent loads: issue before the gather chain
    const float4 rr = r4[(size_t)node * 32 + c];
    const float4 vr = vrel4[c];
    const float4 vo = vroot4[c];

    int j = off[node];
    const int e1 = nend[node];
    float s0 = 0.f, s1 = 0.f, s2 = 0.f, s3 = 0.f;

    // peel one edge if start is odd (align record stream to 16B)
    if ((j & 1) && j < e1) {
        int2 rc = nt_load2(&grec[j]);
        if (half == 0) {
            uint2 v = yb2[(size_t)rc.x * 32 + c];
            float w = __int_as_float(rc.y);
            s0 = fmaf(w, __uint_as_float(v.x << 16), s0);
            s1 = fmaf(w, __uint_as_float(v.x & 0xFFFF0000u), s1);
            s2 = fmaf(w, __uint_as_float(v.y << 16), s2);
            s3 = fmaf(w, __uint_as_float(v.y & 0xFFFF0000u), s3);
        }
        ++j;
    }
    // main: 8 edges/iter; half h owns edges j+4h..j+4h+3
    #pragma unroll 2
    for (; j + 8 <= e1; j += 8) {
        intx4 p0 = nt_load4(&grec[j + 4 * half]);
        intx4 p1 = nt_load4(&grec[j + 4 * half + 2]);
        int srcs[4] = {p0.x, p0.z, p1.x, p1.z};
        float ws[4] = {__int_as_float(p0.y), __int_as_float(p0.w),
                       __int_as_float(p1.y), __int_as_float(p1.w)};
        uint2 v[4];
        #pragma unroll
        for (int u = 0; u < 4; ++u) v[u] = yb2[(size_t)srcs[u] * 32 + c];
        #pragma unroll
        for (int u = 0; u < 4; ++u) {
            s0 = fmaf(ws[u], __uint_as_float(v[u].x << 16), s0);
            s1 = fmaf(ws[u], __uint_as_float(v[u].x & 0xFFFF0000u), s1);
            s2 = fmaf(ws[u], __uint_as_float(v[u].y << 16), s2);
            s3 = fmaf(ws[u], __uint_as_float(v[u].y & 0xFFFF0000u), s3);
        }
    }
    // tail: 2 edges/iter (one per half)
    for (; j < e1; j += 2) {
        int e = j + half;
        if (e < e1) {
            int2 rc = nt_load2(&grec[e]);
            uint2 v = yb2[(size_t)rc.x * 32 + c];
            float w = __int_as_float(rc.y);
            s0 = fmaf(w, __uint_as_float(v.x << 16), s0);
            s1 = fmaf(w, __uint_as_float(v.x & 0xFFFF0000u), s1);
            s2 = fmaf(w, __uint_as_float(v.y << 16), s2);
            s3 = fmaf(w, __uint_as_float(v.y & 0xFFFF0000u), s3);
        }
    }
    // merge the two halves' partial sums
    s0 += __shfl_xor(s0, 32);
    s1 += __shfl_xor(s1, 32);
    s2 += __shfl_xor(s2, 32);
    s3 += __shfl_xor(s3, 32);

    float h0 = fmaxf(s0 + rr.x, 0.f);
    float h1 = fmaxf(s1 + rr.y, 0.f);
    float h2 = fmaxf(s2 + rr.z, 0.f);
    float h3 = fmaxf(s3 + rr.w, 0.f);
    float pa = h0 * vr.x + h1 * vr.y + h2 * vr.z + h3 * vr.w;
    float pb = h0 * vo.x + h1 * vo.y + h2 * vo.z + h3 * vo.w;
    for (int mm = 16; mm > 0; mm >>= 1) {
        pa += __shfl_xor(pa, mm);
        pb += __shfl_xor(pb, mm);
    }
    if (lane == 0) {
        aout[node] = pa;
        bout[node] = pb;
    }
}

// ---------------------------------------------------------------------------
// K4: reduce + final — TWO nodes per wave (32 lanes each; mean degree 32 so
// 64-lane waves were half idle); bin by graph; spread partials; last block
// computes out[]
// ---------------------------------------------------------------------------
__global__ __launch_bounds__(256) void k_reduce_final(
    const int2* __restrict__ grec, const int* __restrict__ off,
    const int* __restrict__ nend,
    const float* __restrict__ a, const float* __restrict__ bvec,
    const int* __restrict__ batch,
    float* __restrict__ gpart, int* __restrict__ gpartc,
    int* __restrict__ ticket_red,
    const float* __restrict__ cb3, const float* __restrict__ blin,
    float* __restrict__ out) {
    __shared__ float sbin[NGRAPH];
    __shared__ int cbin[NGRAPH];
    __shared__ int islast;
    const int t = threadIdx.x;
    for (int i = t; i < NGRAPH; i += 256) { sbin[i] = 0.f; cbin[i] = 0; }
    __syncthreads();
    const int lane = t & 63;
    const int half = lane >> 5;
    const int c = lane & 31;
    const int pw = blockIdx.x * 4 + (t >> 6);
    const int np = gridDim.x * 4;
    for (int pair = pw; pair < N_NODES / 2; pair += np) {   // N_NODES even
        const int node = pair * 2 + half;
        const int e0 = off[node], e1 = nend[node];
        const float bv = bvec[node];   // hoisted independent load
        float s = 0.f;
        for (int j = e0 + c; j < e1; j += 32) {
            int2 rc = nt_load2(&grec[j]);
            s = fmaf(__int_as_float(rc.y), a[rc.x], s);
        }
        for (int mm = 16; mm > 0; mm >>= 1) s += __shfl_xor(s, mm);
        if (c == 0) {
            int g = batch[node];
            atomicAdd(&sbin[g], s + bv);
            atomicAdd(&cbin[g], 1);
        }
    }
    __syncthreads();
    const int slot = blockIdx.x & 63;
    for (int i = t; i < NGRAPH; i += 256) {
        atomicAdd(&gpart[slot * NGRAPH + i], sbin[i]);
        if (cbin[i]) atomicAdd(&gpartc[slot * NGRAPH + i], cbin[i]);
    }
    __syncthreads();
    if (t == 0) {
        __threadfence();
        islast = (atomicAdd(ticket_red, 1) == (int)gridDim.x - 1);
    }
    __syncthreads();
    if (islast) {
        __threadfence();
        if (t < NGRAPH) {
            float S = 0.f;
            int C = 0;
            for (int s2 = 0; s2 < 64; ++s2) {
                S += __hip_atomic_load(&gpart[s2 * NGRAPH + t], __ATOMIC_RELAXED,
                                       __HIP_MEMORY_SCOPE_AGENT);
                C += __hip_atomic_load(&gpartc[s2 * NGRAPH + t], __ATOMIC_RELAXED,
                                       __HIP_MEMORY_SCOPE_AGENT);
            }
            float denom = (C > 0) ? (float)C : 1.f;
            float v = (S + (float)C * cb3[0]) / denom + blin[0];
            out[t] = (v > 0.f) ? v : 0.f;
        }
    }
}

// ---------------------------------------------------------------------------
extern "C" void kernel_launch(void* const* d_in, const int* in_sizes, int n_in,
                              void* d_out, int out_size, void* d_ws, size_t ws_size,
                              hipStream_t stream) {
    const float* x = (const float*)d_in[0];
    const int* edge_index = (const int*)d_in[1];
    const int* src = edge_index;
    const int* dst = edge_index + N_EDGES;
    const int* batch = (const int*)d_in[2];
    const float* ew = (const float*)d_in[3];
    const float* W1rel = (const float*)d_in[4];
    const float* b1 = (const float*)d_in[5];
    const float* W1root = (const float*)d_in[6];
    const float* W3rel = (const float*)d_in[7];
    const float* b3 = (const float*)d_in[8];
    const float* W3root = (const float*)d_in[9];
    const float* Wlin = (const float*)d_in[10];
    const float* blin = (const float*)d_in[11];
    float* out = (float*)d_out;

    char* w = (char*)d_ws;
    size_t o = 0;
    auto alloc = [&](size_t bytes) -> void* {
        void* p = w + o;
        o += bytes;
        o = (o + 255) & ~(size_t)255;
        return p;
    };
    // zero region: gcursor[313] | ticket_red | gpart[64*64] f32 | gpartc[64*64]
    char* zbase = (char*)alloc((NBUCK + 1) * 4 + 64 * NGRAPH * 4 * 2);
    int* gcursor = (int*)zbase;
    int* ticket_red = gcursor + NBUCK;
    float* gpart = (float*)(zbase + (NBUCK + 1) * 4);
    int* gpartc = (int*)(zbase + (NBUCK + 1) * 4 + 64 * NGRAPH * 4);
    const size_t zbytes = (NBUCK + 1) * 4 + 64 * NGRAPH * 4 * 2;

    unsigned short* wbh = (unsigned short*)alloc((size_t)256 * DIM * 2);
    unsigned short* wbl = (unsigned short*)alloc((size_t)256 * DIM * 2);
    unsigned short* yb = (unsigned short*)alloc((size_t)N_NODES * DIM * 2);
    float* r = (float*)alloc((size_t)N_NODES * DIM * 4);
    int2* part = (int2*)alloc((size_t)NBUCK * CAP * 8);   // 6.4 MB padded
    int* off = (int*)alloc((size_t)N_NODES * 4);
    int* nend = (int*)alloc((size_t)N_NODES * 4);
    float* a = (float*)alloc((size_t)N_NODES * 4);
    float* b = (float*)alloc((size_t)N_NODES * 4);
    float* vrel = (float*)alloc(DIM * 4);
    float* vroot = (float*)alloc(DIM * 4);
    float* cb3 = (float*)alloc(4);

    hipMemsetAsync(zbase, 0, zbytes, stream);

    k_part_prep<<<NB_PART + NB_WCONV + 1, 256, 0, stream>>>(
        src, dst, ew, W1rel, W1root, W3rel, W3root, b3, Wlin,
        gcursor, part, wbh, wbl, vrel, vroot, cb3);

    k_sort_gemm<<<NBUCK + NB_GEMM, 256, 0, stream>>>(
        gcursor, part, off, nend, x, wbh, wbl, b1, yb, r);

    k_agg<<<(N_NODES + 3) / 4, 256, 0, stream>>>(
        (const uint2*)yb, (const float4*)r, off, nend, part,
        (const float4*)vrel, (const float4*)vroot, a, b);

    k_reduce_final<<<RED_BLOCKS, 256, 0, stream>>>(
        part, off, nend, a, b, batch, gpart, gpartc, ticket_red, cb3, blin, out);
}